// Round 12
// baseline (331.542 us; speedup 1.0000x reference)
//
#include <hip/hip_runtime.h>

typedef __bf16 bf16x8 __attribute__((ext_vector_type(8)));
typedef float f32x4 __attribute__((ext_vector_type(4)));
typedef unsigned long long u64;

#define NCH 8            // row-chunks per recurrence
#define CELLS 16         // rows per chunk
#define NG 256           // 4 gates * 64 units
#define L2E 1.44269504089f
#define RDEPTH 16                       // ring depth (tag mod 16)
#define NLINK (16 * 7)                  // (g, producer ch 0..6)
#define RING_U64 (NLINK * RDEPTH * 64)  // 896 KiB
#define PROG_OFF (RING_U64 * 8)         // byte offset of progress flags

__device__ __forceinline__ unsigned short f2bfbits(float f) {
  __bf16 b = (__bf16)f;
  return __builtin_bit_cast(unsigned short, b);
}
__device__ __forceinline__ float bfbits2f(unsigned short s) {
  return (float)__builtin_bit_cast(__bf16, s);
}
// LDS-only barrier: vmcnt stays in flight (out stores, x loads, ring ops)
__device__ __forceinline__ void barrier_lds() {
  asm volatile("s_waitcnt lgkmcnt(0)" ::: "memory");
  __builtin_amdgcn_s_barrier();
}
// 16B-granule XOR swizzle for 128B bf16 rows (row 0 identity -> linear).
__device__ __forceinline__ int hix(int row, int byteoff) {
  return row * 128 + (byteoff ^ ((row & 7) << 4));
}
// masked f32x8 -> bf16x8 (invalid -> 0; same rounding as the staged path)
__device__ __forceinline__ bf16x8 pack8(float4 a, float4 b, bool v) {
  bf16x8 r;
  r[0] = (__bf16)(v ? a.x : 0.f);
  r[1] = (__bf16)(v ? a.y : 0.f);
  r[2] = (__bf16)(v ? a.z : 0.f);
  r[3] = (__bf16)(v ? a.w : 0.f);
  r[4] = (__bf16)(v ? b.x : 0.f);
  r[5] = (__bf16)(v ? b.y : 0.f);
  r[6] = (__bf16)(v ? b.z : 0.f);
  r[7] = (__bf16)(v ? b.w : 0.f);
  return r;
}

// ROW-partitioned 2D-LSTM pipeline; 4 SELF-SUFFICIENT compute waves.
// Hypothesis test: R2/R10/R11 nulls say per-step period is pinned neither
// by compute issue, helper work, LDS traffic, nor chain micro-scheduling.
// The untested variable is the 8-wave / 2-per-SIMD organization (issue-port
// sharing + 8-wave barrier spread). This round: 256 thr = 4 waves, 1/SIMD,
// with R10's verified protocol kept BYTE-IDENTICAL (RDEPTH=16, prog/gate,
// lookahead-1, preloop shape, R10 epilogue — R11's regressions reverted):
//  - x loaded per-lane from HBM at step-top for diag d+1 (clamped addr +
//    mask; identical rounding), consumed ~1500cy later in the tail shadow.
//  - ring guard (tag d+1) loaded by hi16==0 lanes at step-top, resolved at
//    step-bottom (same lookahead-1 slack the parity poll had); guards in
//    registers; gbh/gbc deleted.
//  - thread 0: ring-wrap gate pre-validate (issue-early/resolve-late) +
//    prog store — wave-6's exact duties.
// LDS = Pbuf (4 KiB) only; single barrier per step across 4 waves.
__global__ __launch_bounds__(256, 1) void mdrnn_kernel(
    const float* __restrict__ x, const float* __restrict__ Wk,
    const float* __restrict__ Wr, const float* __restrict__ bias,
    float* __restrict__ out, char* __restrict__ ws) {
  __shared__ __align__(16) unsigned char Pbuf[2][CELLS * 128];  // 4 KiB

  u64* __restrict__ ring = (u64*)ws;
  int* __restrict__ prog = (int*)(ws + PROG_OFF);  // 16-int (64B) stride

  const int tid = threadIdx.x;
  const int L = tid & 63;
  const int lo16 = L & 15;
  const int hi16 = L >> 4;
  const int wq = tid >> 6;
  const int u = wq * 16 + lo16;  // unit index

  const int ch = blockIdx.x >> 4;  // bx%8 == g%8 -> chain on one XCD
  const int g = blockIdx.x & 15;
  const int f = g >> 2;
  const int bb = g & 3;
  const int fh = (f >> 1) & 1;
  const int fw = f & 1;
  const int R0 = ch * CELLS;
  const int D1 = R0 + 142;
  const int linkDn = g * 7 + ch - 1;
  const int linkUp = g * 7 + ch;

  for (int i = tid; i < 2 * CELLS * 32; i += 256) ((int*)Pbuf)[i] = 0;

  // ---- constants: all weight sets on every (compute) wave ----
  float bsc[4];
  bf16x8 wkh[4][2], wrh[4][2], wrl[4][2];
  {
    const float* Wrf = Wr + f * (64 * NG);
    const float* Wkf = Wk + f * (64 * NG);
#pragma unroll
    for (int t = 0; t < 4; ++t) {
      const float st = (t == 2) ? (2.f * L2E) : L2E;
      bsc[t] = bias[f * NG + t * 64 + u] * st;
#pragma unroll
      for (int kt = 0; kt < 2; ++kt)
#pragma unroll
        for (int jj = 0; jj < 8; ++jj) {
          int k = kt * 32 + hi16 * 8 + jj;
          float vr = Wrf[k * NG + t * 64 + u] * st;
          __bf16 vh = (__bf16)vr;
          wrh[t][kt][jj] = vh;
          wrl[t][kt][jj] = (__bf16)(vr - (float)vh);
          wkh[t][kt][jj] = (__bf16)(Wkf[k * NG + t * 64 + u] * st);
        }
    }
  }
  int oidx[4], o_pw[4];
  const int ccStep = fw ? -1 : 1;
#pragma unroll
  for (int j = 0; j < 4; ++j) {
    int ro = R0 + hi16 * 4 + j;
    int rr = fh ? 127 - ro : ro;
    int c0 = R0 - ro;
    oidx[j] = ((bb * 128 + rr) * 128 + (fw ? 127 - c0 : c0)) * NG + f * 64 + u;
    o_pw[j] = hix(hi16 * 4 + j, u * 2);
  }
  const int oStep = ccStep * NG;
  int cbase = -hi16 * 4;
  const int o_ph0 = hix(lo16, hi16 * 16);       // presummed A-row lo16, k 0..31
  const int o_ph1 = hix(lo16, 64 + hi16 * 16);  // k 32..63

  // x addressing: this lane owns chunk row xr, channels hi16*8..+7 / +32..
  const int xr = R0 + lo16;
  const int rrx = fh ? 127 - xr : xr;
  const float* xrow = x + ((bb * 128 + rrx) * 128) * 64 + hi16 * 8;

  __syncthreads();  // S0: Pbuf zero-init visible

  // ---- guard preloop (hi16==0 lanes): tags R0-1, R0 ----
  float g_h = 0.f, g_c = 0.f, gh2 = 0.f, cu0 = 0.f;
  int gateSeen = 0;  // thread 0 only
  if (ch > 0 && hi16 == 0) {
#pragma unroll
    for (int k = 0; k < 2; ++k) {
      const int q = R0 - 1 + k;
      const u64* src = ring + ((linkDn * RDEPTH + (q & (RDEPTH - 1))) << 6) + u;
      u64 v;
      int spin = 0;
      for (;;) {
        v = __hip_atomic_load(src, __ATOMIC_RELAXED, __HIP_MEMORY_SCOPE_AGENT);
        if ((unsigned short)(v >> 48) == (unsigned short)q ||
            spin >= (1 << 22))
          break;
        ++spin;
        __builtin_amdgcn_s_sleep(1);
      }
      if (k == 0) {
        gh2 = bfbits2f((unsigned short)(v >> 32));
        cu0 = __uint_as_float((unsigned)v);
        // P(R0-1)[row0][u] = guard h (scale 1; rest of row stays zero)
        *(unsigned short*)(&Pbuf[(R0 + 1) & 1][0] + u * 2) =
            (unsigned short)(v >> 32);
      } else {
        g_h = bfbits2f((unsigned short)(v >> 32));  // tag R0 (for step R0)
        g_c = __uint_as_float((unsigned)v);
      }
    }
    if (tid == 0)
      __hip_atomic_store(&prog[linkDn * 16], R0, __ATOMIC_RELAXED,
                         __HIP_MEMORY_SCOPE_AGENT);
  }

  // ---- prologue: accA(R0) = b + x(R0)@Wk (valid only lo16==0) ----
  f32x4 zacc[4];
  {
    const bool xv = (lo16 == 0);  // col R0-xr = -lo16
    const int cc = fw ? 127 : 0;  // clamped col 0 (flip-adjusted)
    const float* xp = xrow + cc * 64;
    float4 A0 = *(const float4*)(xp);
    float4 A1 = *(const float4*)(xp + 4);
    float4 B0 = *(const float4*)(xp + 32);
    float4 B1 = *(const float4*)(xp + 36);
    bf16x8 a0 = pack8(A0, A1, xv);
    bf16x8 a1 = pack8(B0, B1, xv);
#pragma unroll
    for (int t = 0; t < 4; ++t) {
      zacc[t] = (f32x4){bsc[t], bsc[t], bsc[t], bsc[t]};
      zacc[t] = __builtin_amdgcn_mfma_f32_16x16x32_bf16(a0, wkh[t][0], zacc[t], 0, 0, 0);
      zacc[t] = __builtin_amdgcn_mfma_f32_16x16x32_bf16(a1, wkh[t][1], zacc[t], 0, 0, 0);
    }
  }
  float hnprev[4], csj[4], puv[4];
#pragma unroll
  for (int j = 0; j < 4; ++j) {
    const float ci = (hi16 == 0 && j == 0) ? cu0 : 0.f;
    csj[j] = ci;
    puv[j] = ci;
    hnprev[j] = 0.f;
  }
  __syncthreads();  // S1: P-init row 0 visible

  unsigned char* Pc = &Pbuf[R0 & 1][0];        // written this step
  unsigned char* Pp = &Pbuf[(R0 + 1) & 1][0];  // read this step

  for (int d = R0; d <= D1; ++d) {
    // ---- issue x loads for diag d+1 (consumed in tail shadow) ----
    const int cN = (d + 1) - xr;
    const bool xv = ((unsigned)cN <= 127u);
    const int ccl = cN < 0 ? 0 : (cN > 127 ? 127 : cN);
    const int cc = fw ? 127 - ccl : ccl;
    const float* xp = xrow + cc * 64;
    const float4 XA0 = *(const float4*)(xp);
    const float4 XA1 = *(const float4*)(xp + 4);
    const float4 XB0 = *(const float4*)(xp + 32);
    const float4 XB1 = *(const float4*)(xp + 36);

    // ---- issue guard load for tag d+1 (resolved at step bottom) ----
    const int q = d + 1;
    const bool qLive = (ch > 0) && (hi16 == 0) && (q <= R0 + 126);
    const u64* qs = ring + ((linkDn * RDEPTH + (q & (RDEPTH - 1))) << 6) + u;
    u64 qv = 0;
    if (qLive)
      qv = __hip_atomic_load(qs, __ATOMIC_RELAXED, __HIP_MEMORY_SCOPE_AGENT);

    // ---- issue gate pre-validate for tag d+1 (thread 0) ----
    const int nt = d + 1;
    const bool gatev = (tid == 0) && (ch < NCH - 1) && (nt <= D1) &&
                       (nt >= R0 + 15 + RDEPTH);
    int progNow = gateSeen;
    if (gatev && gateSeen < nt - RDEPTH)
      progNow = __hip_atomic_load(&prog[linkUp * 16], __ATOMIC_RELAXED,
                                  __HIP_MEMORY_SCOPE_AGENT);

    // ---- critical region: P read -> 16 MFMA (R10 4-deep chains) ----
    bf16x8 pa0 = *(const bf16x8*)(Pp + o_ph0);
    bf16x8 pa1 = *(const bf16x8*)(Pp + o_ph1);
    const float gh1 = g_h;  // guard tag d (resolved last step)
    const float gc1 = g_c;
#pragma unroll
    for (int t = 0; t < 4; ++t)
      zacc[t] = __builtin_amdgcn_mfma_f32_16x16x32_bf16(pa0, wrh[t][0], zacc[t], 0, 0, 0);
#pragma unroll
    for (int t = 0; t < 4; ++t)
      zacc[t] = __builtin_amdgcn_mfma_f32_16x16x32_bf16(pa1, wrh[t][1], zacc[t], 0, 0, 0);
#pragma unroll
    for (int t = 0; t < 4; ++t)
      zacc[t] = __builtin_amdgcn_mfma_f32_16x16x32_bf16(pa0, wrl[t][0], zacc[t], 0, 0, 0);
#pragma unroll
    for (int t = 0; t < 4; ++t)
      zacc[t] = __builtin_amdgcn_mfma_f32_16x16x32_bf16(pa1, wrl[t][1], zacc[t], 0, 0, 0);

    const bool pubW = (ch < NCH - 1) && (d >= R0 + 15);

    // ---- epilogue: j=3 first (feeds publish + cross-row shuffles) ----
    float hcur[4], cnew[4];
    {
      const int cj = cbase - 3;
      const bool ok = ((unsigned)cj <= 127u);
      const float inv = (cj == 0) ? 1.f : (1.f / 3.f);  // lm>=3 -> r>0
      const float cpj = csj[3] * inv;
      const float e1 = __builtin_amdgcn_exp2f(-zacc[1][3]);  // zf
      const float e2 = __builtin_amdgcn_exp2f(-zacc[0][3]);  // zi
      const float e3 = __builtin_amdgcn_exp2f(zacc[2][3]);   // zg
      const float A = 1.f + e1, Bv = 1.f + e2, Cv = 1.f + e3;
      const float BC = Bv * Cv;
      float cn = (cpj * BC + (e3 - 1.f) * A) * __builtin_amdgcn_rcpf(A * BC);
      const float e4 = __builtin_amdgcn_exp2f(-zacc[3][3]);  // zo
      const float e5 = __builtin_amdgcn_exp2f(2.f * L2E * cn);
      float hn = (e5 - 1.f) * __builtin_amdgcn_rcpf((1.f + e4) * (1.f + e5));
      if (pubW && hi16 == 3) {  // DIRECT publish: pack + store, no gate
        u64 v = ((u64)(unsigned short)d << 48) | ((u64)f2bfbits(hn) << 32) |
                (u64)__float_as_uint(cn);
        u64* dst = ring + ((linkUp * RDEPTH + (d & (RDEPTH - 1))) << 6) + u;
        __hip_atomic_store(dst, v, __ATOMIC_RELAXED, __HIP_MEMORY_SCOPE_AGENT);
      }
      hcur[3] = ok ? hn : 0.f;
      cnew[3] = ok ? cn : 0.f;
    }
    // issue cross-row shuffles early (hide ds_bpermute under j=2..0)
    const unsigned pk =
        ((unsigned)f2bfbits(hcur[3]) << 16) | f2bfbits(hnprev[3]);
    const unsigned pku = __shfl((int)pk, (L - 16) & 63);
    const float up_c = __shfl(cnew[3], (L - 16) & 63);
#pragma unroll
    for (int jj = 0; jj < 3; ++jj) {
      const int j = 2 - jj;
      const int cj = cbase - j;
      const bool ok = ((unsigned)cj <= 127u);
      const float inv =
          (cj == 0 || (j == 0 && R0 == 0 && hi16 == 0)) ? 1.f : (1.f / 3.f);
      const float cpj = csj[j] * inv;
      const float e1 = __builtin_amdgcn_exp2f(-zacc[1][j]);  // zf
      const float e2 = __builtin_amdgcn_exp2f(-zacc[0][j]);  // zi
      const float e3 = __builtin_amdgcn_exp2f(zacc[2][j]);   // zg
      const float A = 1.f + e1, Bv = 1.f + e2, Cv = 1.f + e3;
      const float BC = Bv * Cv;
      float cn = (cpj * BC + (e3 - 1.f) * A) * __builtin_amdgcn_rcpf(A * BC);
      const float e4 = __builtin_amdgcn_exp2f(-zacc[3][j]);  // zo
      const float e5 = __builtin_amdgcn_exp2f(2.f * L2E * cn);
      float hn = (e5 - 1.f) * __builtin_amdgcn_rcpf((1.f + e4) * (1.f + e5));
      hcur[j] = ok ? hn : 0.f;
      cnew[j] = ok ? cn : 0.f;
    }
    const float up_h = bfbits2f((unsigned short)(pku >> 16));
    const float up_hp = bfbits2f((unsigned short)(pku & 0xffff));

    // ---- producer presum pass: P(d) rows + csj for step d+1 ----
#pragma unroll
    for (int j = 0; j < 4; ++j) {
      const float hup = j ? hcur[j - 1] : (hi16 ? up_h : gh1);
      const float hulp = j ? hnprev[j - 1] : (hi16 ? up_hp : gh2);
      const float sPj =
          ((cbase + 1 == j) || (R0 == 0 && hi16 == 0 && j == 0))
              ? 1.f : (1.f / 3.f);
      *(unsigned short*)(Pc + o_pw[j]) =
          f2bfbits(sPj * (hup + hcur[j] + hulp));
      const float cun = j ? cnew[j - 1] : (hi16 ? up_c : gc1);
      csj[j] = cun + cnew[j] + puv[j];
      puv[j] = cun;
    }
    gh2 = gh1;

    // ---- out stores (pure sinks, off the lgkm path) ----
#pragma unroll
    for (int j = 0; j < 4; ++j) {
      if ((unsigned)(cbase - j) <= 127u) out[oidx[j]] = hcur[j];
      hnprev[j] = hcur[j];
      oidx[j] += oStep;
    }
    ++cbase;

    // ---- tail shadow: accA(d+1) = b + x(d+1)@Wk (loads issued at top) --
    {
      bf16x8 a0 = pack8(XA0, XA1, xv);
      bf16x8 a1 = pack8(XB0, XB1, xv);
#pragma unroll
      for (int t = 0; t < 4; ++t) {
        zacc[t] = (f32x4){bsc[t], bsc[t], bsc[t], bsc[t]};
        zacc[t] = __builtin_amdgcn_mfma_f32_16x16x32_bf16(a0, wkh[t][0], zacc[t], 0, 0, 0);
        zacc[t] = __builtin_amdgcn_mfma_f32_16x16x32_bf16(a1, wkh[t][1], zacc[t], 0, 0, 0);
      }
    }

    // ---- resolve guard tag d+1 (rare spin; pacing of the chain) ----
    if (qLive) {
      int spin = 0;
      while ((unsigned short)(qv >> 48) != (unsigned short)q &&
             spin < (1 << 22)) {
        ++spin;
        __builtin_amdgcn_s_sleep(1);
        qv = __hip_atomic_load(qs, __ATOMIC_RELAXED, __HIP_MEMORY_SCOPE_AGENT);
      }
      g_h = bfbits2f((unsigned short)(qv >> 32));
      g_c = __uint_as_float((unsigned)qv);
    }
    if (ch > 0 && tid == 0)
      __hip_atomic_store(&prog[linkDn * 16], min(d + 1, R0 + 126),
                         __ATOMIC_RELAXED, __HIP_MEMORY_SCOPE_AGENT);
    // ---- resolve gate (thread 0; spins only if downstream lags) ----
    if (gatev) {
      if (progNow > gateSeen) gateSeen = progNow;
      int spin = 0;
      while (gateSeen < nt - RDEPTH && spin < (1 << 22)) {
        ++spin;
        __builtin_amdgcn_s_sleep(1);
        gateSeen = __hip_atomic_load(&prog[linkUp * 16], __ATOMIC_RELAXED,
                                     __HIP_MEMORY_SCOPE_AGENT);
      }
    }

    // rotate P buffers
    {
      unsigned char* t1 = Pc; Pc = Pp; Pp = t1;
    }
    barrier_lds();  // single barrier: P-writes -> next step's P-reads
  }
}

extern "C" void kernel_launch(void* const* d_in, const int* in_sizes, int n_in,
                              void* d_out, int out_size, void* d_ws, size_t ws_size,
                              hipStream_t stream) {
  const float* x = (const float*)d_in[0];
  const float* Wk = (const float*)d_in[1];
  const float* Wr = (const float*)d_in[2];
  const float* b = (const float*)d_in[3];
  float* out = (float*)d_out;
  // reset ring tags + progress flags every launch (graph-replay determinism)
  hipMemsetAsync(d_ws, 0, PROG_OFF + NLINK * 16 * sizeof(int), stream);
  hipLaunchKernelGGL(mdrnn_kernel, dim3(128), dim3(256), 0, stream, x, Wk, Wr,
                     b, out, (char*)d_ws);
}

// Round 13
// 223.129 us; speedup vs baseline: 1.4859x; 1.4859x over previous
//
#include <hip/hip_runtime.h>

typedef __bf16 bf16x8 __attribute__((ext_vector_type(8)));
typedef __bf16 bf16x4 __attribute__((ext_vector_type(4)));
typedef float f32x4 __attribute__((ext_vector_type(4)));
typedef unsigned long long u64;

#define NCH 8            // row-chunks per recurrence
#define CELLS 16         // rows per chunk
#define NG 256           // 4 gates * 64 units
#define L2E 1.44269504089f
#define RDEPTH 16                       // ring depth (tag mod 16)
#define NLINK (16 * 7)                  // (g, producer ch 0..6)
#define RING_U64 (NLINK * RDEPTH * 64)  // 896 KiB
#define PROG_OFF (RING_U64 * 8)         // byte offset of progress flags

__device__ __forceinline__ unsigned short f2bfbits(float f) {
  __bf16 b = (__bf16)f;
  return __builtin_bit_cast(unsigned short, b);
}
__device__ __forceinline__ float bfbits2f(unsigned short s) {
  return (float)__builtin_bit_cast(__bf16, s);
}
// LDS-only barrier: vmcnt stays in flight (out stores, x loads, ring ops)
__device__ __forceinline__ void barrier_lds() {
  asm volatile("s_waitcnt lgkmcnt(0)" ::: "memory");
  __builtin_amdgcn_s_barrier();
}
// 16B-granule XOR swizzle for 128B bf16 rows (row 0 identity -> linear).
__device__ __forceinline__ int hix(int row, int byteoff) {
  return row * 128 + (byteoff ^ ((row & 7) << 4));
}

// ROW-partitioned 2D-LSTM pipeline; WAVE-SPECIALIZED single-barrier step.
// FINAL (session best, verified 222.7us): R10 structure. The experiment
// ledger behind this configuration:
//  - presum/guard-fold (R4), compute-direct publish + wave-6 gate (R5/R6),
//    fill-lag unpinned via preloop-minimal + lookahead-1 polls (R8),
//    zbuf deleted / compute-owned accA shadow (R10): all captured wins.
//  - accA offload (R2), chain micro-scheduling (R11), 4-wave/1-per-SIMD
//    (R9/R12): falsified — 2 waves/SIMD co-scheduling provides ~1000cy/step
//    of latency hiding; the remaining period is the dependency chain
//    (P-read -> 16 MFMA -> LSTM gates -> presum -> P-write -> barrier),
//    tau ~= 260 steps x p ~= 2060 cy. Not a HW-throughput limit
//    (MfmaUtil 5%, VALUBusy 15%, HBM 6%); it is the recurrence's
//    critical path at this decomposition.
// Block = (chunk ch, recurrence g), 512 thr = 8 waves (2/SIMD):
//   waves 0-3 (compute): {2x ds_read_b128 of pre-summed A-rows (P) + x-frag
//     reads (xC = x(d+1)) + guard reads, 16 h@Wr MFMA chained from
//     C=accA, LSTM epilogue (j=3 first -> DIRECT ring publish + early
//     shuffles), presum pass, out stores, shadow accA(d+1) = b + x@Wk}.
//   waves 4-7 (helper): stage x(d+3)->xt tri-buf, prefetch x(d+4).
//     waves 4/5 alternate by parity: resolve ring tag d+1 (issue-early /
//       resolve-late), write gbh/gbc, update prog.
//     wave 6: pre-validates ring-wrap gate for tag d+1 (prog load issued
//       early, checked late; spins only if downstream lags > RDEPTH-1).
__global__ __launch_bounds__(512, 1) void mdrnn_kernel(
    const float* __restrict__ x, const float* __restrict__ Wk,
    const float* __restrict__ Wr, const float* __restrict__ bias,
    float* __restrict__ out, char* __restrict__ ws) {
  __shared__ __align__(16) unsigned char xt[3][CELLS * 128];    // 6 KiB
  __shared__ __align__(16) unsigned char Pbuf[2][CELLS * 128];  // 4 KiB
  __shared__ __align__(16) unsigned char gbh[8 * 128];          // 1 KiB
  __shared__ __align__(16) float gbc[8 * 64];                   // 2 KiB

  u64* __restrict__ ring = (u64*)ws;
  int* __restrict__ prog = (int*)(ws + PROG_OFF);  // 16-int (64B) stride

  const int tid = threadIdx.x;
  const bool isComp = (tid < 256);
  const int L = tid & 63;
  const int lo16 = L & 15;
  const int hi16 = L >> 4;
  const int wq = (tid >> 6) & 3;     // wave id within compute/helper group
  const int u = wq * 16 + lo16;      // unit-group index (both roles)
  const int hm0 = (tid >> 4) & 15;   // helper: staged row
  const int hq16 = tid & 15;         // helper: channel quad

  const int ch = blockIdx.x >> 4;   // bx%8 == g%8 -> chain on one XCD
  const int g = blockIdx.x & 15;
  const int f = g >> 2;
  const int bb = g & 3;
  const int fh = (f >> 1) & 1;
  const int fw = f & 1;
  const int R0 = ch * CELLS;
  const int D1 = R0 + 142;
  const int linkDn = g * 7 + ch - 1;
  const int linkUp = g * 7 + ch;

  for (int i = tid; i < 3 * CELLS * 32; i += 512) ((int*)xt)[i] = 0;
  for (int i = tid; i < 2 * CELLS * 32; i += 512) ((int*)Pbuf)[i] = 0;
  for (int i = tid; i < 8 * 32; i += 512) ((int*)gbh)[i] = 0;
  for (int i = tid; i < 8 * 64; i += 512) gbc[i] = 0.f;

  // ---- compute-wave constants (helpers need no weights) ----
  float bsc[4] = {0.f, 0.f, 0.f, 0.f};
  bf16x8 wkh[4][2], wrh[4][2], wrl[4][2];
  int oidx[4];
  int oStep = 0, cbase = 0;
  int o_ph0 = 0, o_ph1 = 0;
  int o_pw[4] = {0, 0, 0, 0};
  if (isComp) {
    const float* Wrf = Wr + f * (64 * NG);
    const float* Wkf = Wk + f * (64 * NG);
#pragma unroll
    for (int t = 0; t < 4; ++t) {
      const float st = (t == 2) ? (2.f * L2E) : L2E;
      bsc[t] = bias[f * NG + t * 64 + u] * st;
#pragma unroll
      for (int kt = 0; kt < 2; ++kt)
#pragma unroll
        for (int jj = 0; jj < 8; ++jj) {
          int k = kt * 32 + hi16 * 8 + jj;
          float vr = Wrf[k * NG + t * 64 + u] * st;
          __bf16 vh = (__bf16)vr;
          wrh[t][kt][jj] = vh;
          wrl[t][kt][jj] = (__bf16)(vr - (float)vh);
          wkh[t][kt][jj] = (__bf16)(Wkf[k * NG + t * 64 + u] * st);
        }
    }
    const int ccStep = fw ? -1 : 1;
#pragma unroll
    for (int j = 0; j < 4; ++j) {
      int ro = R0 + hi16 * 4 + j;
      int rr = fh ? 127 - ro : ro;
      int c0 = R0 - ro;
      oidx[j] = ((bb * 128 + rr) * 128 + (fw ? 127 - c0 : c0)) * NG + f * 64 + u;
      o_pw[j] = hix(hi16 * 4 + j, u * 2);
    }
    oStep = ccStep * NG;
    cbase = -hi16 * 4;
    o_ph0 = hix(lo16, hi16 * 16);       // presummed A-row lo16, k 0..31
    o_ph1 = hix(lo16, 64 + hi16 * 16);  // k 32..63
  }
  const int o_ax0 = hix(lo16, hi16 * 16);
  const int o_ax1 = hix(lo16, 64 + hi16 * 16);

  // ---- helper-wave x addressing ----
  const int ccStepH = fw ? -1 : 1;
  const int rx = R0 + hm0;
  const int rrx = fh ? 127 - rx : rx;
  int cx = R0 - rx;
  int xidx = ((bb * 128 + rrx) * 128 + (fw ? 127 - cx : cx)) * 64 + hq16 * 4;
  const int xStep = ccStepH * 64;
  float4 px;
  bool pxv = false;
  auto ldg = [&]() {
    pxv = ((unsigned)cx <= 127u);
    px = make_float4(0.f, 0.f, 0.f, 0.f);
    if (pxv) px = *(const float4*)(x + xidx);
    xidx += xStep;
    ++cx;
  };
  auto stx = [&](unsigned char* buf) {
    if (pxv) {
      bf16x4 pk;
      pk[0] = (__bf16)px.x; pk[1] = (__bf16)px.y;
      pk[2] = (__bf16)px.z; pk[3] = (__bf16)px.w;
      *(bf16x4*)(buf + hix(hm0, hq16 * 8)) = pk;
    }
  };

  __syncthreads();  // S0: zero-init visible

  if (!isComp) {
    ldg();                       // px = x(R0)
    stx(&xt[R0 % 3][0]);
    ldg();                       // px = x(R0+1)
  }
  __syncthreads();  // S1: xt(R0) visible

  if (!isComp) {
    stx(&xt[(R0 + 1) % 3][0]);   // stage x(R0+1)
    ldg();                       // px = x(R0+2)
    // pre-loop poll (wave 4): ONLY tags R0-1, R0; in-loop parity polls
    // take over from q=R0+1 (fill-lag unpinned, R8).
    if (wq == 0 && ch > 0) {
#pragma unroll
      for (int k = 0; k < 2; ++k) {
        const int q = R0 - 1 + k;
        u64* src = ring + ((linkDn * RDEPTH + (q & (RDEPTH - 1))) << 6) + L;
        u64 v;
        int spin = 0;
        for (;;) {
          v = __hip_atomic_load(src, __ATOMIC_RELAXED, __HIP_MEMORY_SCOPE_AGENT);
          if ((unsigned short)(v >> 48) == (unsigned short)q ||
              spin >= (1 << 22))
            break;
          ++spin;
          __builtin_amdgcn_s_sleep(1);
        }
        *(unsigned short*)(gbh + (q & 7) * 128 + L * 2) =
            (unsigned short)(v >> 32);
        gbc[(q & 7) * 64 + L] = __uint_as_float((unsigned)v);
        if (k == 0)  // P(R0-1)[row0] = guard h (scale 1; rest stays zero)
          *(unsigned short*)(&Pbuf[(R0 + 1) & 1][0] + L * 2) =
              (unsigned short)(v >> 32);
      }
      if (L == 0)
        __hip_atomic_store(&prog[linkDn * 16], R0, __ATOMIC_RELAXED,
                           __HIP_MEMORY_SCOPE_AGENT);
    }
  }
  __syncthreads();  // S2: xt(R0+1), gbh/gbc, P-init visible

  // ---- compute-wave carried state ----
  f32x4 zacc[4];
  float hnprev[4];  // this lane's h(d-1)[rows lm] (masked)
  float csj[4];     // presummed c for the CURRENT step
  float puv[4];     // carried c_ul = prev step's c_up
  int gateSeen = 0;  // helper wave 6 only
  if (isComp) {
    // prologue accA(R0) = b + x(R0)@Wk directly from xt
    const unsigned char* xp = &xt[R0 % 3][0];
    bf16x8 a0 = *(const bf16x8*)(xp + o_ax0);
    bf16x8 a1 = *(const bf16x8*)(xp + o_ax1);
#pragma unroll
    for (int t = 0; t < 4; ++t) {
      zacc[t] = (f32x4){bsc[t], bsc[t], bsc[t], bsc[t]};
      zacc[t] = __builtin_amdgcn_mfma_f32_16x16x32_bf16(a0, wkh[t][0], zacc[t], 0, 0, 0);
      zacc[t] = __builtin_amdgcn_mfma_f32_16x16x32_bf16(a1, wkh[t][1], zacc[t], 0, 0, 0);
    }
    const float cu0 = gbc[((R0 - 1) & 7) * 64 + u];  // zero for ch==0
#pragma unroll
    for (int j = 0; j < 4; ++j) {
      const float ci = (hi16 == 0 && j == 0) ? cu0 : 0.f;
      csj[j] = ci;
      puv[j] = ci;
      hnprev[j] = 0.f;
    }
    __builtin_amdgcn_s_setprio(1);  // compute waves favored over helpers
  } else {
    stx(&xt[(R0 + 2) % 3][0]);   // stage x(R0+2)
    ldg();                       // px = x(R0+3)
  }
  __syncthreads();  // S3: xt(R0+2) visible

  // rotating pointers (uniform)
  unsigned char* Pc = &Pbuf[R0 & 1][0];        // written this step
  unsigned char* Pp = &Pbuf[(R0 + 1) & 1][0];  // read this step
  unsigned char* xA = &xt[(R0 + 2) % 3][0];    // in-flight (x(d+2))
  unsigned char* xB = &xt[R0 % 3][0];          // stx write (x(d+3))
  unsigned char* xC = &xt[(R0 + 1) % 3][0];    // compute shadow read x(d+1)

  for (int d = R0; d <= D1; ++d) {
    if (isComp) {
      // ---- post-barrier critical region: P read -> 16 MFMA ----
      bf16x8 pa0 = *(const bf16x8*)(Pp + o_ph0);
      bf16x8 pa1 = *(const bf16x8*)(Pp + o_ph1);
      // x-frags for the tail shadow (xC stable all step; latency hides
      // under MFMAs/epilogue)
      bf16x8 a0 = *(const bf16x8*)(xC + o_ax0);
      bf16x8 a1 = *(const bf16x8*)(xC + o_ax1);
      // guard reads hoisted pre-MFMA; row-0 swizzle of gbh is identity.
      const float gh1 = bfbits2f(*(const unsigned short*)(gbh + (d & 7) * 128 + u * 2));
      const float gh2 = bfbits2f(*(const unsigned short*)(gbh + ((d - 1) & 7) * 128 + u * 2));
      const float gc1 = gbc[(d & 7) * 64 + u];
#pragma unroll
      for (int t = 0; t < 4; ++t)
        zacc[t] = __builtin_amdgcn_mfma_f32_16x16x32_bf16(pa0, wrh[t][0], zacc[t], 0, 0, 0);
#pragma unroll
      for (int t = 0; t < 4; ++t)
        zacc[t] = __builtin_amdgcn_mfma_f32_16x16x32_bf16(pa1, wrh[t][1], zacc[t], 0, 0, 0);
#pragma unroll
      for (int t = 0; t < 4; ++t)
        zacc[t] = __builtin_amdgcn_mfma_f32_16x16x32_bf16(pa0, wrl[t][0], zacc[t], 0, 0, 0);
#pragma unroll
      for (int t = 0; t < 4; ++t)
        zacc[t] = __builtin_amdgcn_mfma_f32_16x16x32_bf16(pa1, wrl[t][1], zacc[t], 0, 0, 0);

      const bool pubW = (ch < NCH - 1) && (d >= R0 + 15);

      // ---- epilogue: j=3 first (feeds publish + cross-row shuffles) ----
      float hcur[4], cnew[4];
      {
        const int cj = cbase - 3;
        const bool ok = ((unsigned)cj <= 127u);
        const float inv = (cj == 0) ? 1.f : (1.f / 3.f);  // lm>=3 -> r>0
        const float cpj = csj[3] * inv;
        const float e1 = __builtin_amdgcn_exp2f(-zacc[1][3]);  // zf
        const float e2 = __builtin_amdgcn_exp2f(-zacc[0][3]);  // zi
        const float e3 = __builtin_amdgcn_exp2f(zacc[2][3]);   // zg
        const float A = 1.f + e1, Bv = 1.f + e2, Cv = 1.f + e3;
        const float BC = Bv * Cv;
        float cn = (cpj * BC + (e3 - 1.f) * A) *
                   __builtin_amdgcn_rcpf(A * BC);
        const float e4 = __builtin_amdgcn_exp2f(-zacc[3][3]);  // zo
        const float e5 = __builtin_amdgcn_exp2f(2.f * L2E * cn);
        float hn = (e5 - 1.f) * __builtin_amdgcn_rcpf((1.f + e4) * (1.f + e5));
        if (pubW && hi16 == 3) {  // DIRECT publish: pack + store, no gate
          u64 v = ((u64)(unsigned short)d << 48) | ((u64)f2bfbits(hn) << 32) |
                  (u64)__float_as_uint(cn);
          u64* dst = ring + ((linkUp * RDEPTH + (d & (RDEPTH - 1))) << 6) + u;
          __hip_atomic_store(dst, v, __ATOMIC_RELAXED,
                             __HIP_MEMORY_SCOPE_AGENT);
        }
        hcur[3] = ok ? hn : 0.f;
        cnew[3] = ok ? cn : 0.f;
      }
      // issue cross-row shuffles early (hide ds_bpermute under j=2..0)
      const unsigned pk =
          ((unsigned)f2bfbits(hcur[3]) << 16) | f2bfbits(hnprev[3]);
      const unsigned pku = __shfl((int)pk, (L - 16) & 63);
      const float up_c = __shfl(cnew[3], (L - 16) & 63);
#pragma unroll
      for (int jj = 0; jj < 3; ++jj) {
        const int j = 2 - jj;
        const int cj = cbase - j;
        const bool ok = ((unsigned)cj <= 127u);
        const float inv =
            (cj == 0 || (j == 0 && R0 == 0 && hi16 == 0)) ? 1.f : (1.f / 3.f);
        const float cpj = csj[j] * inv;
        const float e1 = __builtin_amdgcn_exp2f(-zacc[1][j]);  // zf
        const float e2 = __builtin_amdgcn_exp2f(-zacc[0][j]);  // zi
        const float e3 = __builtin_amdgcn_exp2f(zacc[2][j]);   // zg
        const float A = 1.f + e1, Bv = 1.f + e2, Cv = 1.f + e3;
        const float BC = Bv * Cv;
        float cn = (cpj * BC + (e3 - 1.f) * A) *
                   __builtin_amdgcn_rcpf(A * BC);
        const float e4 = __builtin_amdgcn_exp2f(-zacc[3][j]);  // zo
        const float e5 = __builtin_amdgcn_exp2f(2.f * L2E * cn);
        float hn = (e5 - 1.f) * __builtin_amdgcn_rcpf((1.f + e4) * (1.f + e5));
        hcur[j] = ok ? hn : 0.f;
        cnew[j] = ok ? cn : 0.f;
      }
      const float up_h = bfbits2f((unsigned short)(pku >> 16));
      const float up_hp = bfbits2f((unsigned short)(pku & 0xffff));

      // ---- producer presum pass: P(d) rows + csj for step d+1 ----
#pragma unroll
      for (int j = 0; j < 4; ++j) {
        const float hup = j ? hcur[j - 1] : (hi16 ? up_h : gh1);
        const float hulp = j ? hnprev[j - 1] : (hi16 ? up_hp : gh2);
        const float sPj =
            ((cbase + 1 == j) || (R0 == 0 && hi16 == 0 && j == 0))
                ? 1.f : (1.f / 3.f);
        *(unsigned short*)(Pc + o_pw[j]) =
            f2bfbits(sPj * (hup + hcur[j] + hulp));
        const float cun = j ? cnew[j - 1] : (hi16 ? up_c : gc1);
        csj[j] = cun + cnew[j] + puv[j];
        puv[j] = cun;
      }
      // ---- out stores after P-write (pure sinks, off the lgkm path) ----
#pragma unroll
      for (int j = 0; j < 4; ++j) {
        if ((unsigned)(cbase - j) <= 127u) out[oidx[j]] = hcur[j];
        hnprev[j] = hcur[j];
        oidx[j] += oStep;
      }
      ++cbase;

      // ---- tail shadow: accA(d+1) = b + x(d+1)@Wk (frags read at top) --
#pragma unroll
      for (int t = 0; t < 4; ++t) {
        zacc[t] = (f32x4){bsc[t], bsc[t], bsc[t], bsc[t]};
        zacc[t] = __builtin_amdgcn_mfma_f32_16x16x32_bf16(a0, wkh[t][0], zacc[t], 0, 0, 0);
        zacc[t] = __builtin_amdgcn_mfma_f32_16x16x32_bf16(a1, wkh[t][1], zacc[t], 0, 0, 0);
      }
    } else {
      // ---- helpers: poll/gate ISSUE -> stage -> RESOLVE ----
      const bool meAct = (ch > 0) && (wq == ((d - R0) & 1));
      const int q = d + 1;  // lookahead 1
      const bool qLive = meAct && (q >= R0 + 1) && (q <= R0 + 126);
      const u64* qs = ring + ((linkDn * RDEPTH + (q & (RDEPTH - 1))) << 6) + L;
      u64 qv = 0;
      if (qLive)
        qv = __hip_atomic_load(qs, __ATOMIC_RELAXED, __HIP_MEMORY_SCOPE_AGENT);
      // wave 6: pre-validate ring-wrap gate for tag d+1 (compute publishes
      // it next step; barrier orders this pass before that publish).
      const int nt = d + 1;
      const bool gatev = (wq == 2) && (ch < NCH - 1) && (nt <= D1) &&
                         (nt >= R0 + 15 + RDEPTH);
      int progNow = gateSeen;
      if (gatev && gateSeen < nt - RDEPTH)
        progNow = __hip_atomic_load(&prog[linkUp * 16], __ATOMIC_RELAXED,
                                    __HIP_MEMORY_SCOPE_AGENT);

      stx(xB);  // x(d+3)
      ldg();    // px = x(d+4)

      if (qLive) {
        int spin = 0;
        while ((unsigned short)(qv >> 48) != (unsigned short)q &&
               spin < (1 << 22)) {
          ++spin;
          __builtin_amdgcn_s_sleep(1);
          qv = __hip_atomic_load(qs, __ATOMIC_RELAXED,
                                 __HIP_MEMORY_SCOPE_AGENT);
        }
        *(unsigned short*)(gbh + (q & 7) * 128 + L * 2) =
            (unsigned short)(qv >> 32);
        gbc[(q & 7) * 64 + L] = __uint_as_float((unsigned)qv);
      }
      if (meAct && L == 0)
        __hip_atomic_store(&prog[linkDn * 16], min(d + 1, R0 + 126),
                           __ATOMIC_RELAXED, __HIP_MEMORY_SCOPE_AGENT);
      if (gatev) {
        if (progNow > gateSeen) gateSeen = progNow;
        int spin = 0;
        while (gateSeen < nt - RDEPTH && spin < (1 << 22)) {
          ++spin;
          __builtin_amdgcn_s_sleep(1);
          gateSeen = __hip_atomic_load(&prog[linkUp * 16], __ATOMIC_RELAXED,
                                       __HIP_MEMORY_SCOPE_AGENT);
        }
      }
    }

    // rotate buffers (uniform, cheap pointer swaps)
    {
      unsigned char* t0 = xA; xA = xB; xB = xC; xC = t0;
      unsigned char* t1 = Pc; Pc = Pp; Pp = t1;
    }
    barrier_lds();  // single barrier: all LDS writes -> next step's reads
  }
}

extern "C" void kernel_launch(void* const* d_in, const int* in_sizes, int n_in,
                              void* d_out, int out_size, void* d_ws, size_t ws_size,
                              hipStream_t stream) {
  const float* x = (const float*)d_in[0];
  const float* Wk = (const float*)d_in[1];
  const float* Wr = (const float*)d_in[2];
  const float* b = (const float*)d_in[3];
  float* out = (float*)d_out;
  // reset ring tags + progress flags every launch (graph-replay determinism)
  hipMemsetAsync(d_ws, 0, PROG_OFF + NLINK * 16 * sizeof(int), stream);
  hipLaunchKernelGGL(mdrnn_kernel, dim3(128), dim3(512), 0, stream, x, Wk, Wr,
                     b, out, (char*)d_ws);
}